// Round 1
// 565.100 us; speedup vs baseline: 1.4091x; 1.4091x over previous
//
#include <hip/hip_runtime.h>
#include <math.h>

#define B_ 256
#define N_ 4096
#define D_ 128
#define C_ 32

typedef float vf4 __attribute__((ext_vector_type(4)));

// ---------------------------------------------------------------------------
// Main fused kernel: softplus/weights precompute + delta + activations.
// Grid: (N/16) n-chunks  x  (B/32) b-chunks = 256 x 8 = 2048 blocks, 256 thr.
// Each 32-lane group g owns rows n = nc*16 + g + {0,8}; lane covers d0=lane*4.
// Case-side data (cases, softplus(fw), fw*-|dw|, bias) is loaded ONCE into
// registers per group, then reused across 32 b values.
// Wave = groups (g, g+1) -> adjacent n -> each dwordx4 store = 1KB contiguous.
// blockIdx % 8 == nc % 8 -> all b-chunks sharing an n-chunk land on one XCD.
// ---------------------------------------------------------------------------
__global__ __launch_bounds__(256) void main_kernel(
    const float* __restrict__ q,        // [B, D]
    const float* __restrict__ cases,    // [N, D]
    const float* __restrict__ fwin,     // [N, D]
    const float* __restrict__ dwin,     // [N, D]
    const float* __restrict__ bias,     // [N]
    float* __restrict__ delta_out,      // [B, N, D]
    float* __restrict__ act_out) {      // [B, N]
  const int nc   = blockIdx.x & 255;    // n-chunk
  const int bc   = blockIdx.x >> 8;     // b-chunk
  const int g    = threadIdx.x >> 5;    // group 0..7
  const int lane = threadIdx.x & 31;
  const int d0   = lane * 4;
  const int b0   = bc * 32;

  int   n[2];
  vf4   cv[2], fv[2], wv[2];
  float bn[2];
  n[0] = nc * 16 + g;
  n[1] = n[0] + 8;

  #pragma unroll
  for (int j = 0; j < 2; ++j) {
    const size_t off = (size_t)n[j] * D_ + d0;
    const vf4 x = *(const vf4*)(fwin + off);
    const vf4 w = *(const vf4*)(dwin + off);
    vf4 sp, wvj;
    #pragma unroll
    for (int k = 0; k < 4; ++k) {
      const float xv = x[k];
      sp[k]  = (xv > 20.f) ? xv : log1pf(expf(xv));  // stable softplus
      wvj[k] = sp[k] * (-fabsf(w[k]));
    }
    cv[j] = *(const vf4*)(cases + off);
    fv[j] = sp;
    wv[j] = wvj;
    bn[j] = bias[n[j]];
  }

  #pragma unroll 4
  for (int bi = 0; bi < 32; ++bi) {
    const int b = b0 + bi;
    const vf4 qv = *(const vf4*)(q + (size_t)b * D_ + d0);
    #pragma unroll
    for (int j = 0; j < 2; ++j) {
      const vf4 dd = qv - cv[j];
      const vf4 sq = dd * dd;
      const vf4 dl = sq * fv[j];
      __builtin_nontemporal_store(
          dl, (vf4*)(delta_out + ((size_t)b * N_ + n[j]) * D_ + d0));
      const vf4 wa = sq * wv[j];
      float acc = (wa.x + wa.y) + (wa.z + wa.w);
      #pragma unroll
      for (int off = 16; off > 0; off >>= 1)
        acc += __shfl_xor(acc, off, 32);
      const float a = 1.f / (1.f + expf(-(acc + bn[j])));
      if (lane == 0) act_out[(size_t)b * N_ + n[j]] = a;
    }
  }
}

// ---------------------------------------------------------------------------
// Finish kernel: per-b activation sum + y_hat in ONE pass over act.
// One block per b, 1024 threads = 32 groups x 32 c-lanes; each group covers
// n = g*4 + 128*iter (vf4 act loads, 4 target rows per iter, 32 iters).
// ---------------------------------------------------------------------------
__global__ __launch_bounds__(1024) void finish_kernel(
    const float* __restrict__ act,      // [B, N]
    const float* __restrict__ targets,  // [N, C]
    float* __restrict__ y) {            // [B, C]
  const int b = blockIdx.x;
  const int c = threadIdx.x & 31;
  const int g = threadIdx.x >> 5;       // 0..31
  float ys = 0.f, ss = 0.f;
  for (int n0 = g * 4; n0 < N_; n0 += 128) {
    const vf4 a = *(const vf4*)(act + (size_t)b * N_ + n0);
    ys += a.x * targets[(size_t)(n0 + 0) * C_ + c];
    ys += a.y * targets[(size_t)(n0 + 1) * C_ + c];
    ys += a.z * targets[(size_t)(n0 + 2) * C_ + c];
    ys += a.w * targets[(size_t)(n0 + 3) * C_ + c];
    ss += (a.x + a.y) + (a.z + a.w);
  }
  __shared__ float sm_y[32][33];
  __shared__ float sm_s[32];
  sm_y[g][c] = ys;
  if (c == 0) sm_s[g] = ss;
  __syncthreads();
  if (g == 0) {
    float t = 0.f, s = 0.f;
    #pragma unroll
    for (int k = 0; k < 32; ++k) { t += sm_y[k][c]; s += sm_s[k]; }
    y[(size_t)b * C_ + c] = t / (s + 0.01f);
  }
}

// ---------------------------------------------------------------------------
extern "C" void kernel_launch(void* const* d_in, const int* in_sizes, int n_in,
                              void* d_out, int out_size, void* d_ws, size_t ws_size,
                              hipStream_t stream) {
  const float* queries = (const float*)d_in[0];   // [B, D]
  const float* cases   = (const float*)d_in[1];   // [N, D]
  const float* targets = (const float*)d_in[2];   // [N, C]
  const float* fwin    = (const float*)d_in[3];   // [N, D]
  const float* dwin    = (const float*)d_in[4];   // [N, D]
  const float* bias    = (const float*)d_in[5];   // [N]

  float* out   = (float*)d_out;
  float* y_hat = out;                              // [B, C]
  float* act   = out + (size_t)B_ * C_;            // [B, N]
  float* delta = act + (size_t)B_ * N_;            // [B, N, D]

  main_kernel<<<2048, 256, 0, stream>>>(queries, cases, fwin, dwin, bias,
                                        delta, act);
  finish_kernel<<<B_, 1024, 0, stream>>>(act, targets, y_hat);
}